// Round 10
// baseline (743.250 us; speedup 1.0000x reference)
//
#include <hip/hip_runtime.h>
#include <hip/hip_fp16.h>

#define NN 50000
#define NE 800000
#define FIN 256
#define C 64
#define NEG_SLOPE 0.01f
#define SCAN_BLOCKS ((NN + 255) / 256)   // 196
#define NBUCK 196                        // bucket = dst >> 8 (dst < 50176)
#define BCAP 8192                        // per-bucket capacity (mean 4082)
#define EB_CHUNK 2048
#define EB_BLOCKS ((NE + EB_CHUNK - 1) / EB_CHUNK)   // 391

typedef float f32x16 __attribute__((ext_vector_type(16)));

__device__ __forceinline__ float leaky(float v) { return v > 0.f ? v : NEG_SLOPE * v; }

// ---------------------------------------------------------------------------
// K0: h = leaky_relu(x @ Wf + bf).
// lane = node (per-lane-DISTINCT LDS reads: 1 ds_read_b128 -> 64 FMAs),
// wave = col-quarter, weights broadcast via s_load_dwordx16 (L2/K$-hot).
// ---------------------------------------------------------------------------
__global__ __launch_bounds__(256) void k_feat(const float* __restrict__ x,
                                              const float* __restrict__ Wf,
                                              const float* __restrict__ bf,
                                              float* __restrict__ h) {
    __shared__ float4 Sx[64][33];   // 33.8 KB; +1 pad
    const int t = threadIdx.x;
    const int lane = t & 63;
    const int q = __builtin_amdgcn_readfirstlane(t) >> 6;   // col-quarter
    const int base = blockIdx.x * 64;

    const float4* x4 = (const float4*)x;
    float4 acc[4];
#pragma unroll
    for (int cp = 0; cp < 4; ++cp) acc[cp] = make_float4(0.f, 0.f, 0.f, 0.f);

#define FRAG(wreg, xs)                                                      \
    acc[0].x = fmaf(xs, wreg[0],  acc[0].x);                                \
    acc[0].y = fmaf(xs, wreg[1],  acc[0].y);                                \
    acc[0].z = fmaf(xs, wreg[2],  acc[0].z);                                \
    acc[0].w = fmaf(xs, wreg[3],  acc[0].w);                                \
    acc[1].x = fmaf(xs, wreg[4],  acc[1].x);                                \
    acc[1].y = fmaf(xs, wreg[5],  acc[1].y);                                \
    acc[1].z = fmaf(xs, wreg[6],  acc[1].z);                                \
    acc[1].w = fmaf(xs, wreg[7],  acc[1].w);                                \
    acc[2].x = fmaf(xs, wreg[8],  acc[2].x);                                \
    acc[2].y = fmaf(xs, wreg[9],  acc[2].y);                                \
    acc[2].z = fmaf(xs, wreg[10], acc[2].z);                                \
    acc[2].w = fmaf(xs, wreg[11], acc[2].w);                                \
    acc[3].x = fmaf(xs, wreg[12], acc[3].x);                                \
    acc[3].y = fmaf(xs, wreg[13], acc[3].y);                                \
    acc[3].z = fmaf(xs, wreg[14], acc[3].z);                                \
    acc[3].w = fmaf(xs, wreg[15], acc[3].w);

    for (int ph = 0; ph < 2; ++ph) {
#pragma unroll
        for (int i = 0; i < 8; ++i) {
            const int idx = t + i * 256;
            const int row = idx >> 5, c = idx & 31;
            int nn = base + row; if (nn >= NN) nn = NN - 1;
            Sx[row][c] = x4[(size_t)nn * 64 + ph * 32 + c];
        }
        __syncthreads();

        const float* wbase = Wf + (size_t)(ph * 128) * 64 + q * 16;
#pragma unroll
        for (int j = 0; j < 32; ++j) {
            const float4 xv = Sx[lane][j];
            const float* wrow = wbase + (size_t)j * 256;
            f32x16 w0_, w1_, w2_, w3_;
            asm volatile("s_load_dwordx16 %0, %4, 0x0\n\t"
                         "s_load_dwordx16 %1, %4, 0x100\n\t"
                         "s_load_dwordx16 %2, %4, 0x200\n\t"
                         "s_load_dwordx16 %3, %4, 0x300\n\t"
                         "s_waitcnt lgkmcnt(0)"
                         : "=&s"(w0_), "=&s"(w1_), "=&s"(w2_), "=&s"(w3_)
                         : "s"(wrow));
            FRAG(w0_, xv.x)
            FRAG(w1_, xv.y)
            FRAG(w2_, xv.z)
            FRAG(w3_, xv.w)
        }
        __syncthreads();
    }
#undef FRAG

    float4* O = (float4*)Sx;
    const float4* bf4 = (const float4*)bf;
#pragma unroll
    for (int cp = 0; cp < 4; ++cp) {
        const float4 b = bf4[q * 4 + cp];
        float4 r;
        r.x = leaky(acc[cp].x + b.x); r.y = leaky(acc[cp].y + b.y);
        r.z = leaky(acc[cp].z + b.z); r.w = leaky(acc[cp].w + b.w);
        O[lane * 17 + q * 4 + cp] = r;
    }
    __syncthreads();
#pragma unroll
    for (int i = 0; i < 4; ++i) {
        const int idx = t + i * 256;
        const int row = idx >> 4, c = idx & 15;
        const int nn = base + row;
        if (nn < NN) ((float4*)h)[(size_t)nn * 16 + c] = O[row * 17 + c];
    }
}

// ---------------------------------------------------------------------------
// K1: qkvs row (192 floats = 768B): [q f32(64) | k/v half2 kvh[c]=(k,v) |
// skip f32(64)].
// k_feat-r7 structure: lane = node (64/block), wave = col-quarter; weights
// streamed via s_load_dwordx16 (4 rows x 16 cols per j, L2/K$-hot, all SGPR
// element indices compile-time); h via per-lane ds_read_b128 (1 read : 64
// FMAs). Four sequential passes q,k,v,skip; kv packed to half2 after the
// v-pass. Stores are 64B contiguous per lane -> full sectors, no staging.
// ---------------------------------------------------------------------------
__global__ __launch_bounds__(256) void k_qkvs(const float* __restrict__ h,
                                              const float* __restrict__ Wq,
                                              const float* __restrict__ Wk,
                                              const float* __restrict__ Wv,
                                              const float* __restrict__ Ws,
                                              const float* __restrict__ bq,
                                              const float* __restrict__ bk,
                                              const float* __restrict__ bv,
                                              const float* __restrict__ bs,
                                              float* __restrict__ qkvs) {
    __shared__ float4 Sh[64][17];   // 17.4 KB padded h-tile
    const int t = threadIdx.x;
    const int lane = t & 63;
    const int w = __builtin_amdgcn_readfirstlane(t) >> 6;   // col-quarter
    const int base = blockIdx.x * 64;

    // stage 64 node-rows coalesced (4 float4 per thread)
    const float4* h4 = (const float4*)h;
#pragma unroll
    for (int i = 0; i < 4; ++i) {
        const int idx = t + i * 256;
        const int row = idx >> 4, c = idx & 15;
        int n = base + row; if (n >= NN) n = NN - 1;
        Sh[row][c] = h4[(size_t)n * 16 + c];
    }
    __syncthreads();

    const int n = base + lane;
    const bool ok = (n < NN);
    float* orow = qkvs + (size_t)n * 192;
    const int c0 = w << 4;   // this thread's 16-col window

#define MATMUL(Wp, A)                                                        \
    _Pragma("unroll")                                                        \
    for (int j = 0; j < 16; ++j) {                                           \
        const float4 xv = Sh[lane][j];                                       \
        const float* wrow = (Wp) + (size_t)(4 * j) * 64 + c0;                \
        f32x16 w0_, w1_, w2_, w3_;                                           \
        asm volatile("s_load_dwordx16 %0, %4, 0x0\n\t"                       \
                     "s_load_dwordx16 %1, %4, 0x100\n\t"                     \
                     "s_load_dwordx16 %2, %4, 0x200\n\t"                     \
                     "s_load_dwordx16 %3, %4, 0x300\n\t"                     \
                     "s_waitcnt lgkmcnt(0)"                                  \
                     : "=&s"(w0_), "=&s"(w1_), "=&s"(w2_), "=&s"(w3_)        \
                     : "s"(wrow));                                           \
        _Pragma("unroll")                                                    \
        for (int i = 0; i < 16; ++i) {                                       \
            A[i] = fmaf(xv.x, w0_[i], A[i]);                                 \
            A[i] = fmaf(xv.y, w1_[i], A[i]);                                 \
            A[i] = fmaf(xv.z, w2_[i], A[i]);                                 \
            A[i] = fmaf(xv.w, w3_[i], A[i]);                                 \
        }                                                                    \
    }

    // ---- q ----
    {
        float a[16];
#pragma unroll
        for (int i = 0; i < 16; ++i) a[i] = bq[c0 + i];
        MATMUL(Wq, a)
        if (ok) {
#pragma unroll
            for (int i = 0; i < 4; ++i)
                *(float4*)(orow + c0 + 4 * i) =
                    make_float4(a[4 * i], a[4 * i + 1], a[4 * i + 2], a[4 * i + 3]);
        }
    }
    // ---- k then v, pack interleaved half2 ----
    {
        float ak[16], av[16];
#pragma unroll
        for (int i = 0; i < 16; ++i) ak[i] = bk[c0 + i];
        MATMUL(Wk, ak)
#pragma unroll
        for (int i = 0; i < 16; ++i) av[i] = bv[c0 + i];
        MATMUL(Wv, av)
        if (ok) {
            __half2* kvh = (__half2*)(orow + 64);
#pragma unroll
            for (int i = 0; i < 16; ++i)
                kvh[c0 + i] = __floats2half2_rn(ak[i], av[i]);
        }
    }
    // ---- skip ----
    {
        float a[16];
#pragma unroll
        for (int i = 0; i < 16; ++i) a[i] = bs[c0 + i];
        MATMUL(Ws, a)
        if (ok) {
#pragma unroll
            for (int i = 0; i < 4; ++i)
                *(float4*)(orow + 128 + c0 + 4 * i) =
                    make_float4(a[4 * i], a[4 * i + 1], a[4 * i + 2], a[4 * i + 3]);
        }
    }
#undef MATMUL
}

// ---------------------------------------------------------------------------
// Atomic-free CSR build (bucketed counting sort).
// bucket = dst >> 8 (196 buckets). Only LDS atomics + 77K aggregated global
// atomics. Packed record: {x = dst<<16 | src, y = half2(attr)}.
// ---------------------------------------------------------------------------
__global__ __launch_bounds__(256) void k_bucket(const int* __restrict__ ei,
                                                const float* __restrict__ eattr,
                                                int* __restrict__ gcur,
                                                uint2* __restrict__ ebuck) {
    __shared__ int hist[NBUCK], lbase[NBUCK], lcur[NBUCK];
    const int t = threadIdx.x;
    const int base = blockIdx.x * EB_CHUNK;
    if (t < NBUCK) { hist[t] = 0; lcur[t] = 0; }
    __syncthreads();

    int dcache[8];
#pragma unroll
    for (int i = 0; i < 8; ++i) {
        const int e = base + i * 256 + t;
        int d = -1;
        if (e < NE) {
            d = ei[NE + e];
            atomicAdd(&hist[d >> 8], 1);
        }
        dcache[i] = d;
    }
    __syncthreads();
    if (t < NBUCK && hist[t] > 0)
        lbase[t] = atomicAdd(&gcur[t], hist[t]);
    __syncthreads();

#pragma unroll
    for (int i = 0; i < 8; ++i) {
        const int e = base + i * 256 + t;
        const int d = dcache[i];
        if (d >= 0) {
            const int b = d >> 8;
            const int rank = atomicAdd(&lcur[b], 1);
            const __half2 a = __floats2half2_rn(eattr[e * 2], eattr[e * 2 + 1]);
            const unsigned src = (unsigned)ei[e];
            ebuck[(size_t)b * BCAP + lbase[b] + rank] =
                make_uint2(((unsigned)d << 16) | src, *(const unsigned*)&a);
        }
    }
}

// one block per bucket: per-dst counts via LDS -> deg
__global__ __launch_bounds__(256) void k_fin_deg(const int* __restrict__ gcur,
                                                 const uint2* __restrict__ ebuck,
                                                 int* __restrict__ deg) {
    __shared__ int dcnt[256];
    const int t = threadIdx.x;
    const int b = blockIdx.x;
    dcnt[t] = 0;
    __syncthreads();
    const int n = gcur[b];
    for (int i = t; i < n; i += 256) {
        const unsigned x = ebuck[(size_t)b * BCAP + i].x;
        atomicAdd(&dcnt[(x >> 16) & 255], 1);
    }
    __syncthreads();
    const int idx = b * 256 + t;
    if (idx < NN) deg[idx] = dcnt[t];
}

__global__ __launch_bounds__(256) void k_blocksum(const int* __restrict__ deg,
                                                  int* __restrict__ bsum) {
    __shared__ int sh[256];
    const int t = threadIdx.x;
    const int idx = blockIdx.x * 256 + t;
    sh[t] = (idx < NN) ? deg[idx] : 0;
    __syncthreads();
#pragma unroll
    for (int off = 128; off > 0; off >>= 1) {
        if (t < off) sh[t] += sh[t + off];
        __syncthreads();
    }
    if (t == 0) bsum[blockIdx.x] = sh[0];
}

__global__ __launch_bounds__(256) void k_scanb(const int* __restrict__ bsum,
                                               int* __restrict__ boff) {
    __shared__ int sh[256];
    const int t = threadIdx.x;
    const int v = (t < SCAN_BLOCKS) ? bsum[t] : 0;
    sh[t] = v;
    __syncthreads();
#pragma unroll
    for (int off = 1; off < 256; off <<= 1) {
        const int x = (t >= off) ? sh[t - off] : 0;
        __syncthreads();
        sh[t] += x;
        __syncthreads();
    }
    if (t < SCAN_BLOCKS) boff[t] = sh[t] - v;  // exclusive
}

__global__ __launch_bounds__(256) void k_writeptr(const int* __restrict__ deg,
                                                  const int* __restrict__ boff,
                                                  int* __restrict__ row_ptr) {
    __shared__ int sh[256];
    const int t = threadIdx.x;
    const int idx = blockIdx.x * 256 + t;
    const int v = (idx < NN) ? deg[idx] : 0;
    sh[t] = v;
    __syncthreads();
#pragma unroll
    for (int off = 1; off < 256; off <<= 1) {
        const int x = (t >= off) ? sh[t - off] : 0;
        __syncthreads();
        sh[t] += x;
        __syncthreads();
    }
    if (idx < NN) row_ptr[idx] = boff[blockIdx.x] + sh[t] - v;  // exclusive
    if (idx == 0) row_ptr[NN] = NE;
}

// one block per bucket: final scatter with LDS cursors seeded from row_ptr.
__global__ __launch_bounds__(256) void k_fin_scat(const int* __restrict__ gcur,
                                                  const uint2* __restrict__ ebuck,
                                                  const int* __restrict__ row_ptr,
                                                  uint2* __restrict__ erec) {
    __shared__ int pcur[256];
    const int t = threadIdx.x;
    const int b = blockIdx.x;
    const int idx = b * 256 + t;
    pcur[t] = (idx < NN) ? row_ptr[idx] : 0;
    __syncthreads();
    const int n = gcur[b];
    for (int i = t; i < n; i += 256) {
        const uint2 rec = ebuck[(size_t)b * BCAP + i];
        const int d = (rec.x >> 16) & 255;
        const int pos = atomicAdd(&pcur[d], 1);
        erec[pos] = make_uint2(rec.x & 0xFFFFu, rec.y);
    }
}

// ---------------------------------------------------------------------------
// K2: fused conv, 16-lane edge groups, 2-edge unroll per group.
// ---------------------------------------------------------------------------
__global__ __launch_bounds__(256) void k_conv(const int* __restrict__ row_ptr,
                                              const uint2* __restrict__ erec,
                                              const float* __restrict__ We,
                                              const float* __restrict__ qkvs,
                                              float* __restrict__ hout) {
    const int t = threadIdx.x;
    const int lane = t & 63;
    const int g = lane >> 4;          // edge-group 0..3
    const int p = lane & 15;          // channel-quarter position
    const int wv = __builtin_amdgcn_readfirstlane(t) >> 6;
    const int d = blockIdx.x * 4 + wv;
    if (d >= NN) return;

    const float* qrow = qkvs + (size_t)d * 192;
    const float4 q4  = *(const float4*)(qrow + 4 * p);
    const float4 w0  = *(const float4*)(We + 4 * p);
    const float4 w1  = *(const float4*)(We + 64 + 4 * p);

    float pg0 = q4.x * w0.x + q4.y * w0.y + q4.z * w0.z + q4.w * w0.w;
    float pg1 = q4.x * w1.x + q4.y * w1.y + q4.z * w1.z + q4.w * w1.w;
#pragma unroll
    for (int mask = 1; mask <= 8; mask <<= 1) {
        pg0 += __shfl_xor(pg0, mask);
        pg1 += __shfl_xor(pg1, mask);
    }
    const float g0 = pg0, g1 = pg1;

    const int i0 = row_ptr[d], i1 = row_ptr[d + 1];
    const char* kvbase = (const char*)qkvs + 256 + ((size_t)p << 4);

    float m = -1e30f, l = 0.f, S1 = 0.f, S2 = 0.f;
    float4 acc = make_float4(0.f, 0.f, 0.f, 0.f);

    int i = i0 + g;
    for (; i + 4 < i1; i += 8) {       // two edges per group-iteration
        const uint2 ra = erec[i];
        const uint2 rb = erec[i + 4];
        const __half2 aha = *(const __half2*)&ra.y;
        const __half2 ahb = *(const __half2*)&rb.y;
        const float a0a = __low2float(aha), a1a = __high2float(aha);
        const float a0b = __low2float(ahb), a1b = __high2float(ahb);
        const float4 kva = *(const float4*)(kvbase + (size_t)ra.x * 768);
        const float4 kvb = *(const float4*)(kvbase + (size_t)rb.x * 768);
        const __half2* ha = (const __half2*)&kva;
        const __half2* hb = (const __half2*)&kvb;
        const float ka0 = __low2float(ha[0]), va0 = __high2float(ha[0]);
        const float ka1 = __low2float(ha[1]), va1 = __high2float(ha[1]);
        const float ka2 = __low2float(ha[2]), va2 = __high2float(ha[2]);
        const float ka3 = __low2float(ha[3]), va3 = __high2float(ha[3]);
        const float kb0 = __low2float(hb[0]), vb0 = __high2float(hb[0]);
        const float kb1 = __low2float(hb[1]), vb1 = __high2float(hb[1]);
        const float kb2 = __low2float(hb[2]), vb2 = __high2float(hb[2]);
        const float kb3 = __low2float(hb[3]), vb3 = __high2float(hb[3]);
        float da = q4.x * ka0 + q4.y * ka1 + q4.z * ka2 + q4.w * ka3;
        float db = q4.x * kb0 + q4.y * kb1 + q4.z * kb2 + q4.w * kb3;
        da += __shfl_xor(da, 1);  db += __shfl_xor(db, 1);
        da += __shfl_xor(da, 2);  db += __shfl_xor(db, 2);
        da += __shfl_xor(da, 4);  db += __shfl_xor(db, 4);
        da += __shfl_xor(da, 8);  db += __shfl_xor(db, 8);
        const float Pa = (da + g0 * a0a + g1 * a1a) * 0.125f;
        const float Pb = (db + g0 * a0b + g1 * a1b) * 0.125f;
        const float mn = fmaxf(m, fmaxf(Pa, Pb));
        const float s  = __expf(m - mn);
        const float ea = __expf(Pa - mn);
        const float eb = __expf(Pb - mn);
        l = l * s + ea + eb;
        acc.x = acc.x * s + va0 * ea + vb0 * eb;
        acc.y = acc.y * s + va1 * ea + vb1 * eb;
        acc.z = acc.z * s + va2 * ea + vb2 * eb;
        acc.w = acc.w * s + va3 * ea + vb3 * eb;
        S1 = S1 * s + a0a * ea + a0b * eb;
        S2 = S2 * s + a1a * ea + a1b * eb;
        m = mn;
    }
    for (; i < i1; i += 4) {
        const uint2 r = erec[i];
        const __half2 ah = *(const __half2*)&r.y;
        const float a0 = __low2float(ah), a1 = __high2float(ah);
        const float4 kvl = *(const float4*)(kvbase + (size_t)r.x * 768);
        const __half2* hv = (const __half2*)&kvl;
        const float kf0 = __low2float(hv[0]), vf0 = __high2float(hv[0]);
        const float kf1 = __low2float(hv[1]), vf1 = __high2float(hv[1]);
        const float kf2 = __low2float(hv[2]), vf2 = __high2float(hv[2]);
        const float kf3 = __low2float(hv[3]), vf3 = __high2float(hv[3]);
        float dot = q4.x * kf0 + q4.y * kf1 + q4.z * kf2 + q4.w * kf3;
        dot += __shfl_xor(dot, 1);
        dot += __shfl_xor(dot, 2);
        dot += __shfl_xor(dot, 4);
        dot += __shfl_xor(dot, 8);
        const float P = (dot + g0 * a0 + g1 * a1) * 0.125f;
        const float mn = fmaxf(m, P);
        const float s = __expf(m - mn);
        const float e = __expf(P - mn);
        l = l * s + e;
        acc.x = acc.x * s + vf0 * e;
        acc.y = acc.y * s + vf1 * e;
        acc.z = acc.z * s + vf2 * e;
        acc.w = acc.w * s + vf3 * e;
        S1 = S1 * s + a0 * e;
        S2 = S2 * s + a1 * e;
        m = mn;
    }

#pragma unroll
    for (int mask = 16; mask <= 32; mask <<= 1) {
        const float mo  = __shfl_xor(m, mask);
        const float lo  = __shfl_xor(l, mask);
        const float axo = __shfl_xor(acc.x, mask);
        const float ayo = __shfl_xor(acc.y, mask);
        const float azo = __shfl_xor(acc.z, mask);
        const float awo = __shfl_xor(acc.w, mask);
        const float S1o = __shfl_xor(S1, mask);
        const float S2o = __shfl_xor(S2, mask);
        const float mn = fmaxf(m, mo);
        const float sA = __expf(m - mn);
        const float sB = __expf(mo - mn);
        l     = l * sA + lo * sB;
        acc.x = acc.x * sA + axo * sB;
        acc.y = acc.y * sA + ayo * sB;
        acc.z = acc.z * sA + azo * sB;
        acc.w = acc.w * sA + awo * sB;
        S1    = S1 * sA + S1o * sB;
        S2    = S2 * sA + S2o * sB;
        m = mn;
    }

    if (lane < 16) {
        const float inv = (l > 0.f) ? 1.f / l : 0.f;
        const float4 sk = *(const float4*)(qrow + 128 + 4 * p);
        float4 r;
        r.x = leaky((acc.x + S1 * w0.x + S2 * w1.x) * inv + sk.x);
        r.y = leaky((acc.y + S1 * w0.y + S2 * w1.y) * inv + sk.y);
        r.z = leaky((acc.z + S1 * w0.z + S2 * w1.z) * inv + sk.z);
        r.w = leaky((acc.w + S1 * w0.w + S2 * w1.w) * inv + sk.w);
        *(float4*)(hout + (size_t)d * C + 4 * p) = r;
    }
}

extern "C" void kernel_launch(void* const* d_in, const int* in_sizes, int n_in,
                              void* d_out, int out_size, void* d_ws, size_t ws_size,
                              hipStream_t stream) {
    const float* x     = (const float*)d_in[0];
    const int*   ei    = (const int*)d_in[1];
    const float* eattr = (const float*)d_in[2];
    const float* Wf    = (const float*)d_in[3];
    const float* bf    = (const float*)d_in[4];
    const float* Wq    = (const float*)d_in[5];
    const float* bq    = (const float*)d_in[6];
    const float* Wk    = (const float*)d_in[7];
    const float* bk    = (const float*)d_in[8];
    const float* Wv    = (const float*)d_in[9];
    const float* bv    = (const float*)d_in[10];
    const float* We    = (const float*)d_in[11];
    const float* Ws    = (const float*)d_in[12];
    const float* bs    = (const float*)d_in[13];
    float* out = (float*)d_out;

    // workspace layout
    char* p = (char*)d_ws;
    float*  h       = (float*)p;  p += (size_t)NN * C * 4;        // 12.8 MB
    float*  qkvs    = (float*)p;  p += (size_t)NN * 192 * 4;      // 38.4 MB
    int*    deg     = (int*)p;    p += (size_t)NN * 4;
    int*    row_ptr = (int*)p;    p += (size_t)(NN + 1) * 4;
    int*    bsum    = (int*)p;    p += (size_t)SCAN_BLOCKS * 4;
    int*    boff    = (int*)p;    p += (size_t)SCAN_BLOCKS * 4;
    int*    gcur    = (int*)p;    p += (size_t)NBUCK * 4;
    uint2*  erec    = (uint2*)p;  p += (size_t)NE * 8;            // 6.4 MB
    uint2*  ebuck   = (uint2*)p;  p += (size_t)NBUCK * BCAP * 8;  // 12.85 MB

    // One-time per call: atomic-free CSR build
    hipMemsetAsync(gcur, 0, (size_t)NBUCK * 4, stream);
    k_bucket<<<EB_BLOCKS, 256, 0, stream>>>(ei, eattr, gcur, ebuck);
    k_fin_deg<<<NBUCK, 256, 0, stream>>>(gcur, ebuck, deg);
    k_blocksum<<<SCAN_BLOCKS, 256, 0, stream>>>(deg, bsum);
    k_scanb<<<1, 256, 0, stream>>>(bsum, boff);
    k_writeptr<<<SCAN_BLOCKS, 256, 0, stream>>>(deg, boff, row_ptr);
    k_fin_scat<<<NBUCK, 256, 0, stream>>>(gcur, ebuck, row_ptr, erec);

    const int gemm_grid = (NN + 63) / 64;   // 782

    k_feat<<<gemm_grid, 256, 0, stream>>>(x, Wf, bf, h);

    for (int layer = 0; layer < 3; ++layer) {
        k_qkvs<<<gemm_grid, 256, 0, stream>>>(h, Wq, Wk, Wv, Ws,
                                              bq, bk, bv, bs, qkvs);
        float* hout = (layer == 2) ? out : h;
        k_conv<<<(NN + 3) / 4, 256, 0, stream>>>(row_ptr, erec, We, qkvs, hout);
    }
}

// Round 11
// 422.754 us; speedup vs baseline: 1.7581x; 1.7581x over previous
//
#include <hip/hip_runtime.h>
#include <hip/hip_fp16.h>

#define NN 50000
#define NE 800000
#define FIN 256
#define C 64
#define NEG_SLOPE 0.01f
#define SCAN_BLOCKS ((NN + 255) / 256)   // 196
#define NBUCK 196                        // bucket = dst >> 8 (dst < 50176)
#define BCAP 8192                        // per-bucket capacity (mean 4082)
#define EB_CHUNK 2048
#define EB_BLOCKS ((NE + EB_CHUNK - 1) / EB_CHUNK)   // 391

typedef float f32x16 __attribute__((ext_vector_type(16)));

__device__ __forceinline__ float leaky(float v) { return v > 0.f ? v : NEG_SLOPE * v; }

// ---------------------------------------------------------------------------
// Weight transpose: Wt[m][c][k] = W_m[k][c], m in {q,k,v,skip}. 16384 elems.
// ---------------------------------------------------------------------------
__global__ __launch_bounds__(256) void k_tw(const float* __restrict__ Wq,
                                            const float* __restrict__ Wk,
                                            const float* __restrict__ Wv,
                                            const float* __restrict__ Ws,
                                            float* __restrict__ Wt) {
    const int idx = blockIdx.x * 256 + threadIdx.x;
    if (idx >= 4 * 64 * 64) return;
    const int m = idx >> 12, r = idx & 4095, c = r >> 6, k = r & 63;
    const float* W = (m == 0) ? Wq : (m == 1) ? Wk : (m == 2) ? Wv : Ws;
    Wt[idx] = W[k * 64 + c];
}

// ---------------------------------------------------------------------------
// K0: h = leaky_relu(x @ Wf + bf).
// lane = node (per-lane-DISTINCT LDS reads: 1 ds_read_b128 -> 64 FMAs),
// wave = col-quarter, weights broadcast via s_load_dwordx16 (L2/K$-hot).
// ---------------------------------------------------------------------------
__global__ __launch_bounds__(256) void k_feat(const float* __restrict__ x,
                                              const float* __restrict__ Wf,
                                              const float* __restrict__ bf,
                                              float* __restrict__ h) {
    __shared__ float4 Sx[64][33];   // 33.8 KB; +1 pad
    const int t = threadIdx.x;
    const int lane = t & 63;
    const int q = __builtin_amdgcn_readfirstlane(t) >> 6;   // col-quarter
    const int base = blockIdx.x * 64;

    const float4* x4 = (const float4*)x;
    float4 acc[4];
#pragma unroll
    for (int cp = 0; cp < 4; ++cp) acc[cp] = make_float4(0.f, 0.f, 0.f, 0.f);

#define FRAG(wreg, xs)                                                      \
    acc[0].x = fmaf(xs, wreg[0],  acc[0].x);                                \
    acc[0].y = fmaf(xs, wreg[1],  acc[0].y);                                \
    acc[0].z = fmaf(xs, wreg[2],  acc[0].z);                                \
    acc[0].w = fmaf(xs, wreg[3],  acc[0].w);                                \
    acc[1].x = fmaf(xs, wreg[4],  acc[1].x);                                \
    acc[1].y = fmaf(xs, wreg[5],  acc[1].y);                                \
    acc[1].z = fmaf(xs, wreg[6],  acc[1].z);                                \
    acc[1].w = fmaf(xs, wreg[7],  acc[1].w);                                \
    acc[2].x = fmaf(xs, wreg[8],  acc[2].x);                                \
    acc[2].y = fmaf(xs, wreg[9],  acc[2].y);                                \
    acc[2].z = fmaf(xs, wreg[10], acc[2].z);                                \
    acc[2].w = fmaf(xs, wreg[11], acc[2].w);                                \
    acc[3].x = fmaf(xs, wreg[12], acc[3].x);                                \
    acc[3].y = fmaf(xs, wreg[13], acc[3].y);                                \
    acc[3].z = fmaf(xs, wreg[14], acc[3].z);                                \
    acc[3].w = fmaf(xs, wreg[15], acc[3].w);

    for (int ph = 0; ph < 2; ++ph) {
#pragma unroll
        for (int i = 0; i < 8; ++i) {
            const int idx = t + i * 256;
            const int row = idx >> 5, c = idx & 31;
            int nn = base + row; if (nn >= NN) nn = NN - 1;
            Sx[row][c] = x4[(size_t)nn * 64 + ph * 32 + c];
        }
        __syncthreads();

        const float* wbase = Wf + (size_t)(ph * 128) * 64 + q * 16;
#pragma unroll
        for (int j = 0; j < 32; ++j) {
            const float4 xv = Sx[lane][j];
            const float* wrow = wbase + (size_t)j * 256;
            f32x16 w0_, w1_, w2_, w3_;
            asm volatile("s_load_dwordx16 %0, %4, 0x0\n\t"
                         "s_load_dwordx16 %1, %4, 0x100\n\t"
                         "s_load_dwordx16 %2, %4, 0x200\n\t"
                         "s_load_dwordx16 %3, %4, 0x300\n\t"
                         "s_waitcnt lgkmcnt(0)"
                         : "=&s"(w0_), "=&s"(w1_), "=&s"(w2_), "=&s"(w3_)
                         : "s"(wrow));
            FRAG(w0_, xv.x)
            FRAG(w1_, xv.y)
            FRAG(w2_, xv.z)
            FRAG(w3_, xv.w)
        }
        __syncthreads();
    }
#undef FRAG

    float4* O = (float4*)Sx;
    const float4* bf4 = (const float4*)bf;
#pragma unroll
    for (int cp = 0; cp < 4; ++cp) {
        const float4 b = bf4[q * 4 + cp];
        float4 r;
        r.x = leaky(acc[cp].x + b.x); r.y = leaky(acc[cp].y + b.y);
        r.z = leaky(acc[cp].z + b.z); r.w = leaky(acc[cp].w + b.w);
        O[lane * 17 + q * 4 + cp] = r;
    }
    __syncthreads();
#pragma unroll
    for (int i = 0; i < 4; ++i) {
        const int idx = t + i * 256;
        const int row = idx >> 4, c = idx & 15;
        const int nn = base + row;
        if (nn < NN) ((float4*)h)[(size_t)nn * 16 + c] = O[row * 17 + c];
    }
}

// ---------------------------------------------------------------------------
// K1 (round-8 proven structure, NPB 32->16 for occupancy):
// qkvs row (192 floats = 768B): [q f32(64) | k/v fp16 interleaved(128h) |
// skip f32(64)].  Transposed mapping: lane = output column, loop over nodes.
// Per-lane weight column (16 float4 VGPRs); h row broadcast via SGPRs
// (s_load_dwordx16 x4, wave-uniform, h is L2-hot). Stores coalesced.
// ---------------------------------------------------------------------------
#define QKVS_NPB 16   // nodes per block; 50000 = 16*3125 exact

__global__ __launch_bounds__(256) void k_qkvs(const float* __restrict__ h,
                                              const float* __restrict__ Wt,
                                              const float* __restrict__ bq,
                                              const float* __restrict__ bk,
                                              const float* __restrict__ bv,
                                              const float* __restrict__ bs,
                                              float* __restrict__ qkvs) {
    const int t = threadIdx.x;
    const int lane = t & 63;
    const int sec = __builtin_amdgcn_readfirstlane(t) >> 6;
    const int base = blockIdx.x * QKVS_NPB;

    int m, cidx;
    float bias;
    if (sec == 0)      { m = 0; cidx = lane; bias = bq[lane]; }
    else if (sec == 1) { m = 3; cidx = lane; bias = bs[lane]; }
    else {
        cidx = ((sec - 2) << 5) + (lane >> 1);   // k/v column
        m = 1 + (lane & 1);                      // even lane -> Wk, odd -> Wv
        bias = (lane & 1) ? bv[cidx] : bk[cidx];
    }

    const float4* wb = (const float4*)(Wt + ((size_t)m << 12) + ((size_t)cidx << 6));
    float4 w[16];
#pragma unroll
    for (int j = 0; j < 16; ++j) w[j] = wb[j];

    for (int i = 0; i < QKVS_NPB; ++i) {
        const float* hrow = h + (size_t)(base + i) * 64;   // wave-uniform
        f32x16 ha, hb, hc, hd;
        asm volatile("s_load_dwordx16 %0, %4, 0x0\n\t"
                     "s_load_dwordx16 %1, %4, 0x40\n\t"
                     "s_load_dwordx16 %2, %4, 0x80\n\t"
                     "s_load_dwordx16 %3, %4, 0xc0\n\t"
                     "s_waitcnt lgkmcnt(0)"
                     : "=&s"(ha), "=&s"(hb), "=&s"(hc), "=&s"(hd)
                     : "s"(hrow));
        float a0 = 0.f, a1 = 0.f, a2 = 0.f, a3 = 0.f;
#pragma unroll
        for (int j = 0; j < 4; ++j) {
            a0 = fmaf(ha[4 * j + 0], w[j].x, a0);
            a1 = fmaf(ha[4 * j + 1], w[j].y, a1);
            a2 = fmaf(ha[4 * j + 2], w[j].z, a2);
            a3 = fmaf(ha[4 * j + 3], w[j].w, a3);
        }
#pragma unroll
        for (int j = 0; j < 4; ++j) {
            a0 = fmaf(hb[4 * j + 0], w[4 + j].x, a0);
            a1 = fmaf(hb[4 * j + 1], w[4 + j].y, a1);
            a2 = fmaf(hb[4 * j + 2], w[4 + j].z, a2);
            a3 = fmaf(hb[4 * j + 3], w[4 + j].w, a3);
        }
#pragma unroll
        for (int j = 0; j < 4; ++j) {
            a0 = fmaf(hc[4 * j + 0], w[8 + j].x, a0);
            a1 = fmaf(hc[4 * j + 1], w[8 + j].y, a1);
            a2 = fmaf(hc[4 * j + 2], w[8 + j].z, a2);
            a3 = fmaf(hc[4 * j + 3], w[8 + j].w, a3);
        }
#pragma unroll
        for (int j = 0; j < 4; ++j) {
            a0 = fmaf(hd[4 * j + 0], w[12 + j].x, a0);
            a1 = fmaf(hd[4 * j + 1], w[12 + j].y, a1);
            a2 = fmaf(hd[4 * j + 2], w[12 + j].z, a2);
            a3 = fmaf(hd[4 * j + 3], w[12 + j].w, a3);
        }
        const float val = ((a0 + a1) + (a2 + a3)) + bias;
        const int n = base + i;   // always < NN (exact tiling)
        float* orow = qkvs + (size_t)n * 192;
        if (sec == 0) {
            orow[lane] = val;                              // q, f32
        } else if (sec == 1) {
            orow[128 + lane] = val;                        // skip, f32
        } else {
            __half* kvh = (__half*)(orow + 64);
            kvh[((sec - 2) << 6) + lane] = __float2half(val);
        }
    }
}

// ---------------------------------------------------------------------------
// Atomic-free CSR build (bucketed counting sort).
// bucket = dst >> 8 (196 buckets). Only LDS atomics + 77K aggregated global
// atomics. Packed record: {x = dst<<16 | src, y = half2(attr)}.
// ---------------------------------------------------------------------------
__global__ __launch_bounds__(256) void k_bucket(const int* __restrict__ ei,
                                                const float* __restrict__ eattr,
                                                int* __restrict__ gcur,
                                                uint2* __restrict__ ebuck) {
    __shared__ int hist[NBUCK], lbase[NBUCK], lcur[NBUCK];
    const int t = threadIdx.x;
    const int base = blockIdx.x * EB_CHUNK;
    if (t < NBUCK) { hist[t] = 0; lcur[t] = 0; }
    __syncthreads();

    int dcache[8];
#pragma unroll
    for (int i = 0; i < 8; ++i) {
        const int e = base + i * 256 + t;
        int d = -1;
        if (e < NE) {
            d = ei[NE + e];
            atomicAdd(&hist[d >> 8], 1);
        }
        dcache[i] = d;
    }
    __syncthreads();
    if (t < NBUCK && hist[t] > 0)
        lbase[t] = atomicAdd(&gcur[t], hist[t]);
    __syncthreads();

#pragma unroll
    for (int i = 0; i < 8; ++i) {
        const int e = base + i * 256 + t;
        const int d = dcache[i];
        if (d >= 0) {
            const int b = d >> 8;
            const int rank = atomicAdd(&lcur[b], 1);
            const __half2 a = __floats2half2_rn(eattr[e * 2], eattr[e * 2 + 1]);
            const unsigned src = (unsigned)ei[e];
            ebuck[(size_t)b * BCAP + lbase[b] + rank] =
                make_uint2(((unsigned)d << 16) | src, *(const unsigned*)&a);
        }
    }
}

// one block per bucket: per-dst counts via LDS -> deg
__global__ __launch_bounds__(256) void k_fin_deg(const int* __restrict__ gcur,
                                                 const uint2* __restrict__ ebuck,
                                                 int* __restrict__ deg) {
    __shared__ int dcnt[256];
    const int t = threadIdx.x;
    const int b = blockIdx.x;
    dcnt[t] = 0;
    __syncthreads();
    const int n = gcur[b];
    for (int i = t; i < n; i += 256) {
        const unsigned x = ebuck[(size_t)b * BCAP + i].x;
        atomicAdd(&dcnt[(x >> 16) & 255], 1);
    }
    __syncthreads();
    const int idx = b * 256 + t;
    if (idx < NN) deg[idx] = dcnt[t];
}

__global__ __launch_bounds__(256) void k_blocksum(const int* __restrict__ deg,
                                                  int* __restrict__ bsum) {
    __shared__ int sh[256];
    const int t = threadIdx.x;
    const int idx = blockIdx.x * 256 + t;
    sh[t] = (idx < NN) ? deg[idx] : 0;
    __syncthreads();
#pragma unroll
    for (int off = 128; off > 0; off >>= 1) {
        if (t < off) sh[t] += sh[t + off];
        __syncthreads();
    }
    if (t == 0) bsum[blockIdx.x] = sh[0];
}

__global__ __launch_bounds__(256) void k_scanb(const int* __restrict__ bsum,
                                               int* __restrict__ boff) {
    __shared__ int sh[256];
    const int t = threadIdx.x;
    const int v = (t < SCAN_BLOCKS) ? bsum[t] : 0;
    sh[t] = v;
    __syncthreads();
#pragma unroll
    for (int off = 1; off < 256; off <<= 1) {
        const int x = (t >= off) ? sh[t - off] : 0;
        __syncthreads();
        sh[t] += x;
        __syncthreads();
    }
    if (t < SCAN_BLOCKS) boff[t] = sh[t] - v;  // exclusive
}

__global__ __launch_bounds__(256) void k_writeptr(const int* __restrict__ deg,
                                                  const int* __restrict__ boff,
                                                  int* __restrict__ row_ptr) {
    __shared__ int sh[256];
    const int t = threadIdx.x;
    const int idx = blockIdx.x * 256 + t;
    const int v = (idx < NN) ? deg[idx] : 0;
    sh[t] = v;
    __syncthreads();
#pragma unroll
    for (int off = 1; off < 256; off <<= 1) {
        const int x = (t >= off) ? sh[t - off] : 0;
        __syncthreads();
        sh[t] += x;
        __syncthreads();
    }
    if (idx < NN) row_ptr[idx] = boff[blockIdx.x] + sh[t] - v;  // exclusive
    if (idx == 0) row_ptr[NN] = NE;
}

// one block per bucket: final scatter with LDS cursors seeded from row_ptr.
__global__ __launch_bounds__(256) void k_fin_scat(const int* __restrict__ gcur,
                                                  const uint2* __restrict__ ebuck,
                                                  const int* __restrict__ row_ptr,
                                                  uint2* __restrict__ erec) {
    __shared__ int pcur[256];
    const int t = threadIdx.x;
    const int b = blockIdx.x;
    const int idx = b * 256 + t;
    pcur[t] = (idx < NN) ? row_ptr[idx] : 0;
    __syncthreads();
    const int n = gcur[b];
    for (int i = t; i < n; i += 256) {
        const uint2 rec = ebuck[(size_t)b * BCAP + i];
        const int d = (rec.x >> 16) & 255;
        const int pos = atomicAdd(&pcur[d], 1);
        erec[pos] = make_uint2(rec.x & 0xFFFFu, rec.y);
    }
}

// ---------------------------------------------------------------------------
// K2: fused conv, 16-lane edge groups, 2-edge unroll per group.
// ---------------------------------------------------------------------------
__global__ __launch_bounds__(256) void k_conv(const int* __restrict__ row_ptr,
                                              const uint2* __restrict__ erec,
                                              const float* __restrict__ We,
                                              const float* __restrict__ qkvs,
                                              float* __restrict__ hout) {
    const int t = threadIdx.x;
    const int lane = t & 63;
    const int g = lane >> 4;          // edge-group 0..3
    const int p = lane & 15;          // channel-quarter position
    const int wv = __builtin_amdgcn_readfirstlane(t) >> 6;
    const int d = blockIdx.x * 4 + wv;
    if (d >= NN) return;

    const float* qrow = qkvs + (size_t)d * 192;
    const float4 q4  = *(const float4*)(qrow + 4 * p);
    const float4 w0  = *(const float4*)(We + 4 * p);
    const float4 w1  = *(const float4*)(We + 64 + 4 * p);

    float pg0 = q4.x * w0.x + q4.y * w0.y + q4.z * w0.z + q4.w * w0.w;
    float pg1 = q4.x * w1.x + q4.y * w1.y + q4.z * w1.z + q4.w * w1.w;
#pragma unroll
    for (int mask = 1; mask <= 8; mask <<= 1) {
        pg0 += __shfl_xor(pg0, mask);
        pg1 += __shfl_xor(pg1, mask);
    }
    const float g0 = pg0, g1 = pg1;

    const int i0 = row_ptr[d], i1 = row_ptr[d + 1];
    const char* kvbase = (const char*)qkvs + 256 + ((size_t)p << 4);

    float m = -1e30f, l = 0.f, S1 = 0.f, S2 = 0.f;
    float4 acc = make_float4(0.f, 0.f, 0.f, 0.f);

    int i = i0 + g;
    for (; i + 4 < i1; i += 8) {       // two edges per group-iteration
        const uint2 ra = erec[i];
        const uint2 rb = erec[i + 4];
        const __half2 aha = *(const __half2*)&ra.y;
        const __half2 ahb = *(const __half2*)&rb.y;
        const float a0a = __low2float(aha), a1a = __high2float(aha);
        const float a0b = __low2float(ahb), a1b = __high2float(ahb);
        const float4 kva = *(const float4*)(kvbase + (size_t)ra.x * 768);
        const float4 kvb = *(const float4*)(kvbase + (size_t)rb.x * 768);
        const __half2* ha = (const __half2*)&kva;
        const __half2* hb = (const __half2*)&kvb;
        const float ka0 = __low2float(ha[0]), va0 = __high2float(ha[0]);
        const float ka1 = __low2float(ha[1]), va1 = __high2float(ha[1]);
        const float ka2 = __low2float(ha[2]), va2 = __high2float(ha[2]);
        const float ka3 = __low2float(ha[3]), va3 = __high2float(ha[3]);
        const float kb0 = __low2float(hb[0]), vb0 = __high2float(hb[0]);
        const float kb1 = __low2float(hb[1]), vb1 = __high2float(hb[1]);
        const float kb2 = __low2float(hb[2]), vb2 = __high2float(hb[2]);
        const float kb3 = __low2float(hb[3]), vb3 = __high2float(hb[3]);
        float da = q4.x * ka0 + q4.y * ka1 + q4.z * ka2 + q4.w * ka3;
        float db = q4.x * kb0 + q4.y * kb1 + q4.z * kb2 + q4.w * kb3;
        da += __shfl_xor(da, 1);  db += __shfl_xor(db, 1);
        da += __shfl_xor(da, 2);  db += __shfl_xor(db, 2);
        da += __shfl_xor(da, 4);  db += __shfl_xor(db, 4);
        da += __shfl_xor(da, 8);  db += __shfl_xor(db, 8);
        const float Pa = (da + g0 * a0a + g1 * a1a) * 0.125f;
        const float Pb = (db + g0 * a0b + g1 * a1b) * 0.125f;
        const float mn = fmaxf(m, fmaxf(Pa, Pb));
        const float s  = __expf(m - mn);
        const float ea = __expf(Pa - mn);
        const float eb = __expf(Pb - mn);
        l = l * s + ea + eb;
        acc.x = acc.x * s + va0 * ea + vb0 * eb;
        acc.y = acc.y * s + va1 * ea + vb1 * eb;
        acc.z = acc.z * s + va2 * ea + vb2 * eb;
        acc.w = acc.w * s + va3 * ea + vb3 * eb;
        S1 = S1 * s + a0a * ea + a0b * eb;
        S2 = S2 * s + a1a * ea + a1b * eb;
        m = mn;
    }
    for (; i < i1; i += 4) {
        const uint2 r = erec[i];
        const __half2 ah = *(const __half2*)&r.y;
        const float a0 = __low2float(ah), a1 = __high2float(ah);
        const float4 kvl = *(const float4*)(kvbase + (size_t)r.x * 768);
        const __half2* hv = (const __half2*)&kvl;
        const float kf0 = __low2float(hv[0]), vf0 = __high2float(hv[0]);
        const float kf1 = __low2float(hv[1]), vf1 = __high2float(hv[1]);
        const float kf2 = __low2float(hv[2]), vf2 = __high2float(hv[2]);
        const float kf3 = __low2float(hv[3]), vf3 = __high2float(hv[3]);
        float dot = q4.x * kf0 + q4.y * kf1 + q4.z * kf2 + q4.w * kf3;
        dot += __shfl_xor(dot, 1);
        dot += __shfl_xor(dot, 2);
        dot += __shfl_xor(dot, 4);
        dot += __shfl_xor(dot, 8);
        const float P = (dot + g0 * a0 + g1 * a1) * 0.125f;
        const float mn = fmaxf(m, P);
        const float s = __expf(m - mn);
        const float e = __expf(P - mn);
        l = l * s + e;
        acc.x = acc.x * s + vf0 * e;
        acc.y = acc.y * s + vf1 * e;
        acc.z = acc.z * s + vf2 * e;
        acc.w = acc.w * s + vf3 * e;
        S1 = S1 * s + a0 * e;
        S2 = S2 * s + a1 * e;
        m = mn;
    }

#pragma unroll
    for (int mask = 16; mask <= 32; mask <<= 1) {
        const float mo  = __shfl_xor(m, mask);
        const float lo  = __shfl_xor(l, mask);
        const float axo = __shfl_xor(acc.x, mask);
        const float ayo = __shfl_xor(acc.y, mask);
        const float azo = __shfl_xor(acc.z, mask);
        const float awo = __shfl_xor(acc.w, mask);
        const float S1o = __shfl_xor(S1, mask);
        const float S2o = __shfl_xor(S2, mask);
        const float mn = fmaxf(m, mo);
        const float sA = __expf(m - mn);
        const float sB = __expf(mo - mn);
        l     = l * sA + lo * sB;
        acc.x = acc.x * sA + axo * sB;
        acc.y = acc.y * sA + ayo * sB;
        acc.z = acc.z * sA + azo * sB;
        acc.w = acc.w * sA + awo * sB;
        S1    = S1 * sA + S1o * sB;
        S2    = S2 * sA + S2o * sB;
        m = mn;
    }

    if (lane < 16) {
        const float inv = (l > 0.f) ? 1.f / l : 0.f;
        const float4 sk = *(const float4*)(qrow + 128 + 4 * p);
        float4 r;
        r.x = leaky((acc.x + S1 * w0.x + S2 * w1.x) * inv + sk.x);
        r.y = leaky((acc.y + S1 * w0.y + S2 * w1.y) * inv + sk.y);
        r.z = leaky((acc.z + S1 * w0.z + S2 * w1.z) * inv + sk.z);
        r.w = leaky((acc.w + S1 * w0.w + S2 * w1.w) * inv + sk.w);
        *(float4*)(hout + (size_t)d * C + 4 * p) = r;
    }
}

extern "C" void kernel_launch(void* const* d_in, const int* in_sizes, int n_in,
                              void* d_out, int out_size, void* d_ws, size_t ws_size,
                              hipStream_t stream) {
    const float* x     = (const float*)d_in[0];
    const int*   ei    = (const int*)d_in[1];
    const float* eattr = (const float*)d_in[2];
    const float* Wf    = (const float*)d_in[3];
    const float* bf    = (const float*)d_in[4];
    const float* Wq    = (const float*)d_in[5];
    const float* bq    = (const float*)d_in[6];
    const float* Wk    = (const float*)d_in[7];
    const float* bk    = (const float*)d_in[8];
    const float* Wv    = (const float*)d_in[9];
    const float* bv    = (const float*)d_in[10];
    const float* We    = (const float*)d_in[11];
    const float* Ws    = (const float*)d_in[12];
    const float* bs    = (const float*)d_in[13];
    float* out = (float*)d_out;

    // workspace layout
    char* p = (char*)d_ws;
    float*  h       = (float*)p;  p += (size_t)NN * C * 4;        // 12.8 MB
    float*  qkvs    = (float*)p;  p += (size_t)NN * 192 * 4;      // 38.4 MB
    float*  Wt      = (float*)p;  p += (size_t)4 * 64 * 64 * 4;   // 64 KB
    int*    deg     = (int*)p;    p += (size_t)NN * 4;
    int*    row_ptr = (int*)p;    p += (size_t)(NN + 1) * 4;
    int*    bsum    = (int*)p;    p += (size_t)SCAN_BLOCKS * 4;
    int*    boff    = (int*)p;    p += (size_t)SCAN_BLOCKS * 4;
    int*    gcur    = (int*)p;    p += (size_t)NBUCK * 4;
    uint2*  erec    = (uint2*)p;  p += (size_t)NE * 8;            // 6.4 MB
    uint2*  ebuck   = (uint2*)p;  p += (size_t)NBUCK * BCAP * 8;  // 12.85 MB

    // One-time per call: weight transpose + atomic-free CSR build
    k_tw<<<64, 256, 0, stream>>>(Wq, Wk, Wv, Ws, Wt);
    hipMemsetAsync(gcur, 0, (size_t)NBUCK * 4, stream);
    k_bucket<<<EB_BLOCKS, 256, 0, stream>>>(ei, eattr, gcur, ebuck);
    k_fin_deg<<<NBUCK, 256, 0, stream>>>(gcur, ebuck, deg);
    k_blocksum<<<SCAN_BLOCKS, 256, 0, stream>>>(deg, bsum);
    k_scanb<<<1, 256, 0, stream>>>(bsum, boff);
    k_writeptr<<<SCAN_BLOCKS, 256, 0, stream>>>(deg, boff, row_ptr);
    k_fin_scat<<<NBUCK, 256, 0, stream>>>(gcur, ebuck, row_ptr, erec);

    const int gemm_grid = (NN + 63) / 64;   // 782 (k_feat)
    const int qkvs_grid = NN / QKVS_NPB;    // 3125 exact

    k_feat<<<gemm_grid, 256, 0, stream>>>(x, Wf, bf, h);

    for (int layer = 0; layer < 3; ++layer) {
        k_qkvs<<<qkvs_grid, 256, 0, stream>>>(h, Wt, bq, bk, bv, bs, qkvs);
        float* hout = (layer == 2) ? out : h;
        k_conv<<<(NN + 3) / 4, 256, 0, stream>>>(row_ptr, erec, We, qkvs, hout);
    }
}